// Round 1
// baseline (416.783 us; speedup 1.0000x reference)
//
#include <hip/hip_runtime.h>
#include <math.h>

// Problem constants (match reference)
#define NN 10000
#define EE 320000
#define F_IN 256
#define HID 256
#define C_OUT 40
#define NB 10
#define NREL 2

// ---------------------------------------------------------------------------
// CSR build kernels
// ---------------------------------------------------------------------------
__global__ void zero_i32(int* __restrict__ p, int n) {
    int i = blockIdx.x * 256 + threadIdx.x;
    if (i < n) p[i] = 0;
}

__global__ void count_edges(const int* __restrict__ ei, const int* __restrict__ et,
                            int* __restrict__ cnt, int E_) {
    int e = blockIdx.x * 256 + threadIdx.x;
    if (e < E_) {
        int dst = ei[E_ + e];
        int r = et[e];
        atomicAdd(&cnt[dst * 2 + r], 1);
    }
}

// Single-block exclusive scan over M2 = 2N entries (M2 <= 1024*32)
__global__ __launch_bounds__(1024) void scan_kernel(const int* __restrict__ cnt,
                                                    int* __restrict__ off,
                                                    int* __restrict__ cursor, int M2) {
    __shared__ int part[1024];
    int tid = threadIdx.x;
    int C = (M2 + 1023) / 1024;
    int b0 = tid * C;
    int s = 0;
    for (int i = 0; i < C; ++i) {
        int idx = b0 + i;
        if (idx < M2) s += cnt[idx];
    }
    part[tid] = s;
    __syncthreads();
    // Hillis-Steele inclusive scan
    for (int d = 1; d < 1024; d <<= 1) {
        int t = (tid >= d) ? part[tid - d] : 0;
        __syncthreads();
        part[tid] += t;
        __syncthreads();
    }
    int base = part[tid] - s;  // exclusive
    for (int i = 0; i < C; ++i) {
        int idx = b0 + i;
        if (idx < M2) {
            off[idx] = base;
            cursor[idx] = base;
            base += cnt[idx];
        }
    }
    if (tid == 1023) off[M2] = part[1023];
}

__global__ void fill_edges(const int* __restrict__ ei, const int* __restrict__ et,
                           int* __restrict__ cursor, int* __restrict__ elist, int E_) {
    int e = blockIdx.x * 256 + threadIdx.x;
    if (e < E_) {
        int src = ei[e];
        int dst = ei[E_ + e];
        int r = et[e];
        int pos = atomicAdd(&cursor[dst * 2 + r], 1);
        elist[pos] = src;
    }
}

// ---------------------------------------------------------------------------
// Build concatenated weights: Wcat[768][dout] = [root(256); W0(256); W1(256)]
// W_r = sum_b comp[r][b] * basis[b]   (basis: [NB][256][dout])
// ---------------------------------------------------------------------------
__global__ void build_w(const float* __restrict__ basis, const float* __restrict__ comp,
                        const float* __restrict__ root, float* __restrict__ Wcat, int dout) {
    int idx = blockIdx.x * 256 + threadIdx.x;
    if (idx >= 768 * dout) return;
    int k = idx / dout;
    int n = idx - k * dout;
    float v;
    if (k < 256) {
        v = root[k * dout + n];
    } else {
        int r = (k - 256) >> 8;
        int i = (k - 256) & 255;
        v = 0.f;
#pragma unroll
        for (int b = 0; b < NB; ++b)
            v += comp[r * NB + b] * basis[(b * 256 + i) * dout + n];
    }
    Wcat[idx] = v;
}

// ---------------------------------------------------------------------------
// Aggregation: per node n, per rel r: agg[n][r*256 + f] = mean of h[src][f]
// over incoming rel-r edges. One block per node, thread = feature column.
// ---------------------------------------------------------------------------
__global__ __launch_bounds__(256) void agg_kernel(const float* __restrict__ h,
                                                  const int* __restrict__ off,
                                                  const int* __restrict__ elist,
                                                  float* __restrict__ agg) {
    int n = blockIdx.x;
    int tid = threadIdx.x;
    __shared__ int sl[256];
#pragma unroll
    for (int r = 0; r < NREL; ++r) {
        int idx = n * 2 + r;
        int o0 = off[idx];
        int c = off[idx + 1] - o0;
        float acc = 0.f;
        for (int cb = 0; cb < c; cb += 256) {
            int m = min(256, c - cb);
            __syncthreads();
            if (tid < m) sl[tid] = elist[o0 + cb + tid];
            __syncthreads();
            for (int j = 0; j < m; ++j)
                acc += h[sl[j] * 256 + tid];
        }
        float inv = (c > 0) ? 1.f / (float)c : 0.f;
        agg[n * 512 + r * 256 + tid] = acc * inv;
        __syncthreads();
    }
}

// ---------------------------------------------------------------------------
// Fused GEMM: C[M][Nout] = relu?( [A0 | A1](M x 768) @ B(768 x Nout) + bias )
// A0: [M][256] (h), A1: [M][512] (agg). Tile 64x64, BK=16, 256 thr, 4x4/thread.
// ---------------------------------------------------------------------------
#define BM 64
#define BN 64
#define BK 16

__global__ __launch_bounds__(256) void gemm_rgcn(const float* __restrict__ A0,
                                                 const float* __restrict__ A1,
                                                 const float* __restrict__ B,
                                                 const float* __restrict__ bias,
                                                 float* __restrict__ C, int M, int Nout,
                                                 int relu) {
    __shared__ float As[BK][BM + 4];
    __shared__ float Bs[BK][BN + 4];
    int tid = threadIdx.x;
    int tx = tid & 15;   // col group (B)
    int ty = tid >> 4;   // row group (A)
    int row0 = blockIdx.y * BM;
    int col0 = blockIdx.x * BN;

    // staging indices
    int ar = tid >> 2;         // 0..63 row in A tile
    int ac = (tid & 3) * 4;    // 0,4,8,12 col in k-tile
    int br = tid >> 4;         // 0..15 k row in B tile
    int bc = (tid & 15) * 4;   // 0..60 col in B tile

    float acc[4][4] = {};

    for (int k0 = 0; k0 < 768; k0 += BK) {
        // A tile
        {
            int grow = row0 + ar;
            float4 v = make_float4(0.f, 0.f, 0.f, 0.f);
            if (grow < M) {
                const float* src = (k0 < 256) ? (A0 + grow * 256 + k0 + ac)
                                              : (A1 + grow * 512 + (k0 - 256) + ac);
                v = *(const float4*)src;
            }
            As[ac + 0][ar] = v.x;
            As[ac + 1][ar] = v.y;
            As[ac + 2][ar] = v.z;
            As[ac + 3][ar] = v.w;
        }
        // B tile
        {
            int gk = k0 + br;
            int gc = col0 + bc;
            float4 v;
            if (gc + 3 < Nout) {
                v = *(const float4*)(B + gk * Nout + gc);
            } else {
                v.x = (gc + 0 < Nout) ? B[gk * Nout + gc + 0] : 0.f;
                v.y = (gc + 1 < Nout) ? B[gk * Nout + gc + 1] : 0.f;
                v.z = (gc + 2 < Nout) ? B[gk * Nout + gc + 2] : 0.f;
                v.w = (gc + 3 < Nout) ? B[gk * Nout + gc + 3] : 0.f;
            }
            *(float4*)&Bs[br][bc] = v;
        }
        __syncthreads();
#pragma unroll
        for (int k = 0; k < BK; ++k) {
            float4 a = *(const float4*)&As[k][ty << 2];
            float4 b = *(const float4*)&Bs[k][tx << 2];
            float av[4] = {a.x, a.y, a.z, a.w};
            float bv[4] = {b.x, b.y, b.z, b.w};
#pragma unroll
            for (int i = 0; i < 4; ++i)
#pragma unroll
                for (int j = 0; j < 4; ++j)
                    acc[i][j] = fmaf(av[i], bv[j], acc[i][j]);
        }
        __syncthreads();
    }

#pragma unroll
    for (int i = 0; i < 4; ++i) {
        int r = row0 + (ty << 2) + i;
        if (r >= M) continue;
#pragma unroll
        for (int j = 0; j < 4; ++j) {
            int c = col0 + (tx << 2) + j;
            if (c < Nout) {
                float v = acc[i][j] + bias[c];
                if (relu) v = fmaxf(v, 0.f);
                C[r * Nout + c] = v;
            }
        }
    }
}

// ---------------------------------------------------------------------------
// In-place log_softmax over rows of 40 (one wave per row)
// ---------------------------------------------------------------------------
__global__ __launch_bounds__(256) void logsoftmax40(float* __restrict__ out, int M) {
    int tid = threadIdx.x;
    int lane = tid & 63;
    int wv = tid >> 6;
    int row = blockIdx.x * 4 + wv;
    if (row >= M) return;
    float v = (lane < C_OUT) ? out[row * C_OUT + lane] : -INFINITY;
    float mx = v;
#pragma unroll
    for (int d = 32; d; d >>= 1) mx = fmaxf(mx, __shfl_xor(mx, d, 64));
    float e = (lane < C_OUT) ? expf(v - mx) : 0.f;
    float s = e;
#pragma unroll
    for (int d = 32; d; d >>= 1) s += __shfl_xor(s, d, 64);
    if (lane < C_OUT) out[row * C_OUT + lane] = v - mx - logf(s);
}

// ---------------------------------------------------------------------------
extern "C" void kernel_launch(void* const* d_in, const int* in_sizes, int n_in,
                              void* d_out, int out_size, void* d_ws, size_t ws_size,
                              hipStream_t stream) {
    const float* x = (const float*)d_in[0];
    const int* ei = (const int*)d_in[1];
    const int* et = (const int*)d_in[2];
    const float* basis1 = (const float*)d_in[3];
    const float* comp1 = (const float*)d_in[4];
    const float* root1 = (const float*)d_in[5];
    const float* bias1 = (const float*)d_in[6];
    const float* basis2 = (const float*)d_in[7];
    const float* comp2 = (const float*)d_in[8];
    const float* root2 = (const float*)d_in[9];
    const float* bias2 = (const float*)d_in[10];
    const float* basis3 = (const float*)d_in[11];
    const float* comp3 = (const float*)d_in[12];
    const float* root3 = (const float*)d_in[13];
    const float* bias3 = (const float*)d_in[14];

    int N_ = in_sizes[0] / F_IN;
    int E_ = in_sizes[2];
    int M2 = 2 * N_;

    // workspace carve-up (256B aligned)
    char* p = (char*)d_ws;
    size_t o = 0;
    auto alloc = [&](size_t bytes) {
        void* r = p + o;
        o += (bytes + 255) & ~(size_t)255;
        return r;
    };
    int* cnt = (int*)alloc(M2 * 4);
    int* off = (int*)alloc((M2 + 1) * 4);
    int* cur = (int*)alloc(M2 * 4);
    int* elist = (int*)alloc(E_ * 4);
    float* W1 = (float*)alloc(768 * 256 * 4);
    float* W2 = (float*)alloc(768 * 256 * 4);
    float* W3 = (float*)alloc(768 * C_OUT * 4);
    float* agg = (float*)alloc((size_t)N_ * 512 * 4);
    float* h1 = (float*)alloc((size_t)N_ * 256 * 4);
    float* h2 = (float*)alloc((size_t)N_ * 256 * 4);
    (void)ws_size;

    // --- CSR build (once, reused by all 3 layers) ---
    zero_i32<<<(M2 + 255) / 256, 256, 0, stream>>>(cnt, M2);
    count_edges<<<(E_ + 255) / 256, 256, 0, stream>>>(ei, et, cnt, E_);
    scan_kernel<<<1, 1024, 0, stream>>>(cnt, off, cur, M2);
    fill_edges<<<(E_ + 255) / 256, 256, 0, stream>>>(ei, et, cur, elist, E_);

    // --- weights ---
    build_w<<<(768 * 256 + 255) / 256, 256, 0, stream>>>(basis1, comp1, root1, W1, 256);
    build_w<<<(768 * 256 + 255) / 256, 256, 0, stream>>>(basis2, comp2, root2, W2, 256);
    build_w<<<(768 * C_OUT + 255) / 256, 256, 0, stream>>>(basis3, comp3, root3, W3, C_OUT);

    int mblocks = (N_ + BM - 1) / BM;

    // --- layer 1 ---
    agg_kernel<<<N_, 256, 0, stream>>>(x, off, elist, agg);
    {
        dim3 g(256 / BN, mblocks);
        gemm_rgcn<<<g, 256, 0, stream>>>(x, agg, W1, bias1, h1, N_, 256, 1);
    }
    // --- layer 2 ---
    agg_kernel<<<N_, 256, 0, stream>>>(h1, off, elist, agg);
    {
        dim3 g(256 / BN, mblocks);
        gemm_rgcn<<<g, 256, 0, stream>>>(h1, agg, W2, bias2, h2, N_, 256, 1);
    }
    // --- layer 3 ---
    agg_kernel<<<N_, 256, 0, stream>>>(h2, off, elist, agg);
    {
        dim3 g(1, mblocks);
        gemm_rgcn<<<g, 256, 0, stream>>>(h2, agg, W3, bias3, (float*)d_out, N_, C_OUT, 0);
    }
    // --- log_softmax in-place on d_out ---
    logsoftmax40<<<(N_ + 3) / 4, 256, 0, stream>>>((float*)d_out, N_);
}

// Round 2
// 322.887 us; speedup vs baseline: 1.2908x; 1.2908x over previous
//
#include <hip/hip_runtime.h>
#include <math.h>

#define NREL 2
#define NB 10
#define C_OUT 40

typedef unsigned int u32;
typedef unsigned short u16;
typedef __attribute__((ext_vector_type(8))) short bf16x8;
typedef __attribute__((ext_vector_type(4))) float f32x4;

#define MFMA16 __builtin_amdgcn_mfma_f32_16x16x32_bf16

// split-bf16 packing: u32 = (bf16(v) << 16) | bf16(v - bf16(v))
__device__ __forceinline__ u32 pack_split(float v) {
    u32 u = __float_as_uint(v);
    u32 hi = (u + 0x7FFFu + ((u >> 16) & 1u)) & 0xFFFF0000u;  // RNE to bf16
    float r = v - __uint_as_float(hi);
    u32 ur = __float_as_uint(r);
    u32 lo = ((ur + 0x7FFFu + ((ur >> 16) & 1u)) >> 16) & 0xFFFFu;
    return hi | lo;
}
__device__ __forceinline__ float unpack_val(u32 p) {
    return __uint_as_float(p & 0xFFFF0000u) + __uint_as_float(p << 16);
}

// ---------------------------------------------------------------------------
// CSR build
// ---------------------------------------------------------------------------
__global__ void zero_i32(int* __restrict__ p, int n) {
    int i = blockIdx.x * 256 + threadIdx.x;
    if (i < n) p[i] = 0;
}

__global__ void count_edges(const int* __restrict__ ei, const int* __restrict__ et,
                            int* __restrict__ cnt, int E_) {
    int e = blockIdx.x * 256 + threadIdx.x;
    if (e < E_) {
        int dst = ei[E_ + e];
        int r = et[e];
        atomicAdd(&cnt[dst * 2 + r], 1);
    }
}

__global__ __launch_bounds__(1024) void scan_kernel(const int* __restrict__ cnt,
                                                    int* __restrict__ off,
                                                    int* __restrict__ cursor, int M2) {
    __shared__ int part[1024];
    int tid = threadIdx.x;
    int C = (M2 + 1023) / 1024;
    int b0 = tid * C;
    int s = 0;
    for (int i = 0; i < C; ++i) {
        int idx = b0 + i;
        if (idx < M2) s += cnt[idx];
    }
    part[tid] = s;
    __syncthreads();
    for (int d = 1; d < 1024; d <<= 1) {
        int t = (tid >= d) ? part[tid - d] : 0;
        __syncthreads();
        part[tid] += t;
        __syncthreads();
    }
    int base = part[tid] - s;
    for (int i = 0; i < C; ++i) {
        int idx = b0 + i;
        if (idx < M2) {
            off[idx] = base;
            cursor[idx] = base;
            base += cnt[idx];
        }
    }
    if (tid == 1023) off[M2] = part[1023];
}

__global__ void fill_edges(const int* __restrict__ ei, const int* __restrict__ et,
                           int* __restrict__ cursor, int* __restrict__ elist, int E_) {
    int e = blockIdx.x * 256 + threadIdx.x;
    if (e < E_) {
        int src = ei[e];
        int dst = ei[E_ + e];
        int r = et[e];
        int pos = atomicAdd(&cursor[dst * 2 + r], 1);
        elist[pos] = src;
    }
}

// ---------------------------------------------------------------------------
// Weight build: Wt[c][k] packed split-bf16, k in [0,768): root | W0 | W1, transposed
// ---------------------------------------------------------------------------
__global__ void build_wt(const float* __restrict__ basis, const float* __restrict__ comp,
                         const float* __restrict__ root, u32* __restrict__ Wt,
                         int dout_real, int dout_pad) {
    int idx = blockIdx.x * 256 + threadIdx.x;
    if (idx >= dout_pad * 768) return;
    int c = idx / 768;
    int k = idx - c * 768;
    float v = 0.f;
    if (c < dout_real) {
        if (k < 256) {
            v = root[k * dout_real + c];
        } else {
            int r = (k - 256) >> 8;
            int i = (k - 256) & 255;
#pragma unroll
            for (int b = 0; b < NB; ++b)
                v += comp[r * NB + b] * basis[(b * 256 + i) * dout_real + c];
        }
    }
    Wt[idx] = pack_split(v);
}

// ---------------------------------------------------------------------------
// x -> packed split-bf16
// ---------------------------------------------------------------------------
__global__ void convert_x(const float* __restrict__ x, u32* __restrict__ xP, int n) {
    int i = blockIdx.x * 256 + threadIdx.x;
    if (i < n) xP[i] = pack_split(x[i]);
}

// ---------------------------------------------------------------------------
// Aggregation on packed features: agg[n][r*256+f] = mean over rel-r in-edges
// ---------------------------------------------------------------------------
__global__ __launch_bounds__(256) void agg_packed(const u32* __restrict__ hP,
                                                  const int* __restrict__ off,
                                                  const int* __restrict__ elist,
                                                  u32* __restrict__ aggP) {
    int n = blockIdx.x;
    int tid = threadIdx.x;
    __shared__ int sl[256];
#pragma unroll
    for (int r = 0; r < NREL; ++r) {
        int idx = n * 2 + r;
        int o0 = off[idx];
        int c = off[idx + 1] - o0;
        float acc = 0.f;
        for (int cb = 0; cb < c; cb += 256) {
            int m = min(256, c - cb);
            __syncthreads();
            if (tid < m) sl[tid] = elist[o0 + cb + tid];
            __syncthreads();
            for (int j = 0; j < m; ++j)
                acc += unpack_val(hP[(size_t)sl[j] * 256 + tid]);
        }
        float inv = (c > 0) ? 1.f / (float)c : 0.f;
        aggP[(size_t)n * 512 + r * 256 + tid] = pack_split(acc * inv);
        __syncthreads();
    }
}

// ---------------------------------------------------------------------------
// MFMA GEMM (layers 1,2): Out[M][256] = relu([A0|A1](M x 768) @ W + bias), packed io
// Block: 64 rows x 128 cols, 4 waves (2x2), wave = 32 rows x 64 cols.
// W k-chunk (32) staged in LDS, 80B col pitch (conflict-free), prefetch 1 step.
// ---------------------------------------------------------------------------
__global__ __launch_bounds__(256) void gemm_mfma_big(
    const u32* __restrict__ A0, const u32* __restrict__ A1,
    const u32* __restrict__ Wt, const float* __restrict__ bias,
    u32* __restrict__ OutP, int M) {
    __shared__ u16 ldsB[2][128][40];  // [plane][col][32k + 8 pad]
    int tid = threadIdx.x;
    int lane = tid & 63;
    int w = tid >> 6;
    int wr = w >> 1, wc = w & 1;
    int rb0 = blockIdx.y * 64;
    int cb0 = blockIdx.x * 128;
    int l15 = lane & 15, l4 = lane >> 4;

    int arow0 = rb0 + wr * 32 + l15;

    // staging decomposition: unit = i*256 + tid; col = unit>>2, u = unit&3 (8 k each)
    int su_col[2], su_u[2];
#pragma unroll
    for (int i = 0; i < 2; ++i) {
        int unit = i * 256 + tid;
        su_col[i] = unit >> 2;
        su_u[i] = unit & 3;
    }

    f32x4 acc[2][4] = {};
    uint4 sa0[2], sa1[2];

    // prefetch k=0 staging
#pragma unroll
    for (int i = 0; i < 2; ++i) {
        const uint4* p = (const uint4*)(Wt + (size_t)(cb0 + su_col[i]) * 768 + su_u[i] * 8);
        sa0[i] = p[0];
        sa1[i] = p[1];
    }

    for (int kk = 0; kk < 768; kk += 32) {
        __syncthreads();
        // write staged W chunk to LDS (split planes)
#pragma unroll
        for (int i = 0; i < 2; ++i) {
            u32 s[8] = {sa0[i].x, sa0[i].y, sa0[i].z, sa0[i].w,
                        sa1[i].x, sa1[i].y, sa1[i].z, sa1[i].w};
            bf16x8 h, l;
#pragma unroll
            for (int j = 0; j < 8; ++j) {
                h[j] = (short)(s[j] >> 16);
                l[j] = (short)(s[j] & 0xFFFFu);
            }
            *(bf16x8*)&ldsB[0][su_col[i]][su_u[i] * 8] = h;
            *(bf16x8*)&ldsB[1][su_col[i]][su_u[i] * 8] = l;
        }
        __syncthreads();
        // prefetch next chunk
        if (kk + 32 < 768) {
#pragma unroll
            for (int i = 0; i < 2; ++i) {
                const uint4* p = (const uint4*)(Wt + (size_t)(cb0 + su_col[i]) * 768 +
                                                (kk + 32) + su_u[i] * 8);
                sa0[i] = p[0];
                sa1[i] = p[1];
            }
        }

        // A fragments (global, packed)
        bf16x8 ah[2], al[2];
#pragma unroll
        for (int rt = 0; rt < 2; ++rt) {
            int r = arow0 + rt * 16;
            const u32* base = (kk < 256) ? (A0 + (size_t)r * 256 + kk)
                                         : (A1 + (size_t)r * 512 + (kk - 256));
            const uint4* pa = (const uint4*)(base + l4 * 8);
            uint4 a0 = pa[0], a1 = pa[1];
            u32 s[8] = {a0.x, a0.y, a0.z, a0.w, a1.x, a1.y, a1.z, a1.w};
            bf16x8 h, l;
#pragma unroll
            for (int j = 0; j < 8; ++j) {
                h[j] = (short)(s[j] >> 16);
                l[j] = (short)(s[j] & 0xFFFFu);
            }
            ah[rt] = h;
            al[rt] = l;
        }

        // B fragments from LDS + MFMA (3 products for split precision)
#pragma unroll
        for (int ct = 0; ct < 4; ++ct) {
            int col = wc * 64 + ct * 16 + l15;
            bf16x8 bh = *(const bf16x8*)&ldsB[0][col][l4 * 8];
            bf16x8 bl = *(const bf16x8*)&ldsB[1][col][l4 * 8];
#pragma unroll
            for (int rt = 0; rt < 2; ++rt) {
                acc[rt][ct] = MFMA16(ah[rt], bh, acc[rt][ct], 0, 0, 0);
                acc[rt][ct] = MFMA16(ah[rt], bl, acc[rt][ct], 0, 0, 0);
                acc[rt][ct] = MFMA16(al[rt], bh, acc[rt][ct], 0, 0, 0);
            }
        }
    }

    // epilogue: bias + relu + pack
#pragma unroll
    for (int rt = 0; rt < 2; ++rt) {
#pragma unroll
        for (int ct = 0; ct < 4; ++ct) {
            int col = cb0 + wc * 64 + ct * 16 + l15;
            float b = bias[col];
#pragma unroll
            for (int j = 0; j < 4; ++j) {
                int row = rb0 + wr * 32 + rt * 16 + l4 * 4 + j;
                if (row < M) {
                    float v = acc[rt][ct][j] + b;
                    v = fmaxf(v, 0.f);
                    OutP[(size_t)row * 256 + col] = pack_split(v);
                }
            }
        }
    }
}

// ---------------------------------------------------------------------------
// MFMA GEMM (layer 3): Out[M][40] fp32 = [A0|A1] @ W3 + bias  (W3 padded to 48 cols)
// Block: 4 waves x 16 rows; B-frags straight from global (L2-resident, 147KB)
// ---------------------------------------------------------------------------
__global__ __launch_bounds__(256) void gemm_mfma_small(
    const u32* __restrict__ A0, const u32* __restrict__ A1,
    const u32* __restrict__ Wt, const float* __restrict__ bias,
    float* __restrict__ Out, int M) {
    int tid = threadIdx.x;
    int lane = tid & 63;
    int w = tid >> 6;
    int l15 = lane & 15, l4 = lane >> 4;
    int row0 = blockIdx.x * 64 + w * 16;
    int arow = row0 + l15;

    f32x4 acc[3] = {};

    for (int kk = 0; kk < 768; kk += 32) {
        const u32* base = (kk < 256) ? (A0 + (size_t)arow * 256 + kk)
                                     : (A1 + (size_t)arow * 512 + (kk - 256));
        const uint4* pa = (const uint4*)(base + l4 * 8);
        uint4 a0 = pa[0], a1 = pa[1];
        u32 s[8] = {a0.x, a0.y, a0.z, a0.w, a1.x, a1.y, a1.z, a1.w};
        bf16x8 ah, al;
#pragma unroll
        for (int j = 0; j < 8; ++j) {
            ah[j] = (short)(s[j] >> 16);
            al[j] = (short)(s[j] & 0xFFFFu);
        }
#pragma unroll
        for (int ct = 0; ct < 3; ++ct) {
            int col = ct * 16 + l15;
            const uint4* pb = (const uint4*)(Wt + (size_t)col * 768 + kk + l4 * 8);
            uint4 b0 = pb[0], b1 = pb[1];
            u32 t[8] = {b0.x, b0.y, b0.z, b0.w, b1.x, b1.y, b1.z, b1.w};
            bf16x8 bh, bl;
#pragma unroll
            for (int j = 0; j < 8; ++j) {
                bh[j] = (short)(t[j] >> 16);
                bl[j] = (short)(t[j] & 0xFFFFu);
            }
            acc[ct] = MFMA16(ah, bh, acc[ct], 0, 0, 0);
            acc[ct] = MFMA16(ah, bl, acc[ct], 0, 0, 0);
            acc[ct] = MFMA16(al, bh, acc[ct], 0, 0, 0);
        }
    }

#pragma unroll
    for (int ct = 0; ct < 3; ++ct) {
        int col = ct * 16 + l15;
        if (col < C_OUT) {
            float b = bias[col];
#pragma unroll
            for (int j = 0; j < 4; ++j) {
                int row = row0 + l4 * 4 + j;
                if (row < M) Out[(size_t)row * C_OUT + col] = acc[ct][j] + b;
            }
        }
    }
}

// ---------------------------------------------------------------------------
// log_softmax over rows of 40 (one wave per row)
// ---------------------------------------------------------------------------
__global__ __launch_bounds__(256) void logsoftmax40(float* __restrict__ out, int M) {
    int tid = threadIdx.x;
    int lane = tid & 63;
    int wv = tid >> 6;
    int row = blockIdx.x * 4 + wv;
    if (row >= M) return;
    float v = (lane < C_OUT) ? out[row * C_OUT + lane] : -INFINITY;
    float mx = v;
#pragma unroll
    for (int d = 32; d; d >>= 1) mx = fmaxf(mx, __shfl_xor(mx, d, 64));
    float e = (lane < C_OUT) ? expf(v - mx) : 0.f;
    float s = e;
#pragma unroll
    for (int d = 32; d; d >>= 1) s += __shfl_xor(s, d, 64);
    if (lane < C_OUT) out[row * C_OUT + lane] = v - mx - logf(s);
}

// ---------------------------------------------------------------------------
extern "C" void kernel_launch(void* const* d_in, const int* in_sizes, int n_in,
                              void* d_out, int out_size, void* d_ws, size_t ws_size,
                              hipStream_t stream) {
    const float* x = (const float*)d_in[0];
    const int* ei = (const int*)d_in[1];
    const int* et = (const int*)d_in[2];
    const float* basis1 = (const float*)d_in[3];
    const float* comp1 = (const float*)d_in[4];
    const float* root1 = (const float*)d_in[5];
    const float* bias1 = (const float*)d_in[6];
    const float* basis2 = (const float*)d_in[7];
    const float* comp2 = (const float*)d_in[8];
    const float* root2 = (const float*)d_in[9];
    const float* bias2 = (const float*)d_in[10];
    const float* basis3 = (const float*)d_in[11];
    const float* comp3 = (const float*)d_in[12];
    const float* root3 = (const float*)d_in[13];
    const float* bias3 = (const float*)d_in[14];

    int N_ = in_sizes[0] / 256;
    int E_ = in_sizes[2];
    int M2 = 2 * N_;
    int Mpad = (N_ + 63) & ~63;  // row-padded buffers so OOB A-frag reads stay in ws

    char* p = (char*)d_ws;
    size_t o = 0;
    auto alloc = [&](size_t bytes) {
        void* r = p + o;
        o += (bytes + 255) & ~(size_t)255;
        return r;
    };
    int* cnt = (int*)alloc((size_t)M2 * 4);
    int* off = (int*)alloc((size_t)(M2 + 1) * 4);
    int* cur = (int*)alloc((size_t)M2 * 4);
    int* elist = (int*)alloc((size_t)E_ * 4);
    u32* Wt1 = (u32*)alloc((size_t)256 * 768 * 4);
    u32* Wt2 = (u32*)alloc((size_t)256 * 768 * 4);
    u32* Wt3 = (u32*)alloc((size_t)48 * 768 * 4);
    u32* xP = (u32*)alloc((size_t)Mpad * 256 * 4);
    u32* h1P = (u32*)alloc((size_t)Mpad * 256 * 4);
    u32* aggP = (u32*)alloc((size_t)Mpad * 512 * 4);
    u32* h2P = xP;  // alias: x is dead after layer 1
    (void)ws_size;

    // CSR build (reused by all layers)
    zero_i32<<<(M2 + 255) / 256, 256, 0, stream>>>(cnt, M2);
    count_edges<<<(E_ + 255) / 256, 256, 0, stream>>>(ei, et, cnt, E_);
    scan_kernel<<<1, 1024, 0, stream>>>(cnt, off, cur, M2);
    fill_edges<<<(E_ + 255) / 256, 256, 0, stream>>>(ei, et, cur, elist, E_);

    // weights (transposed + split-packed)
    build_wt<<<(256 * 768 + 255) / 256, 256, 0, stream>>>(basis1, comp1, root1, Wt1, 256, 256);
    build_wt<<<(256 * 768 + 255) / 256, 256, 0, stream>>>(basis2, comp2, root2, Wt2, 256, 256);
    build_wt<<<(48 * 768 + 255) / 256, 256, 0, stream>>>(basis3, comp3, root3, Wt3, 40, 48);

    convert_x<<<(N_ * 256 + 255) / 256, 256, 0, stream>>>(x, xP, N_ * 256);

    int mblocks = (N_ + 63) / 64;

    // layer 1
    agg_packed<<<N_, 256, 0, stream>>>(xP, off, elist, aggP);
    {
        dim3 g(2, mblocks);
        gemm_mfma_big<<<g, 256, 0, stream>>>(xP, aggP, Wt1, bias1, h1P, N_);
    }
    // layer 2
    agg_packed<<<N_, 256, 0, stream>>>(h1P, off, elist, aggP);
    {
        dim3 g(2, mblocks);
        gemm_mfma_big<<<g, 256, 0, stream>>>(h1P, aggP, Wt2, bias2, h2P, N_);
    }
    // layer 3
    agg_packed<<<N_, 256, 0, stream>>>(h2P, off, elist, aggP);
    gemm_mfma_small<<<mblocks, 256, 0, stream>>>(h2P, aggP, Wt3, bias3, (float*)d_out, N_);

    logsoftmax40<<<(N_ + 3) / 4, 256, 0, stream>>>((float*)d_out, N_);
}